// Round 1
// baseline (267.049 us; speedup 1.0000x reference)
//
#include <hip/hip_runtime.h>
#include <hip/hip_bf16.h>

// Problem constants (from reference setup_inputs)
#define N_PARENT 50000
#define C_IN     256
#define C_OUT    256
#define FANOUT   8
#define N_TGT    200000
#define N_UP     (N_PARENT * FANOUT)   // 400000 upsampled rows
#define NCOL     (FANOUT * C_OUT)      // 2048 = fused (k,d) GEMM-N

// Workspace layout (needs ~1.06 MB)
#define OFF_B  0u                       // bf16 BbT[j=2048][c=256]  (B^T, 1 MB)
#define OFF_V  (1u << 20)               // float V[8][256] = W_up[k] @ W_cls (8 KB)
#define OFF_EB (OFF_V + 8192u)          // float ebias = b_up . W_cls + b_cls

typedef __attribute__((ext_vector_type(8))) short short8;
typedef __attribute__((ext_vector_type(4))) float floatx4;

static __device__ __forceinline__ unsigned short f2bf(float f) {
    return __builtin_bit_cast(unsigned short, __float2bfloat16(f));
}

// ---------------------------------------------------------------------------
// Kernel 1: build BbT (bf16 B^T: BbT[k*256+d][c] = W_up[k][c][d]),
//           V[k][c] = sum_d W_up[k][c][d] * W_cls[d],
//           ebias   = sum_d b_up[d] * W_cls[d] + b_cls.
// Grid: 2048 blocks (= k*256 + c), 256 threads (= d).
// ---------------------------------------------------------------------------
__global__ __launch_bounds__(256) void prep_kernel(
        const float* __restrict__ W_up, const float* __restrict__ b_up,
        const float* __restrict__ W_cls, const float* __restrict__ b_cls,
        unsigned char* __restrict__ ws) {
    __shared__ float sm[4];
    const int bid = blockIdx.x;
    const int k = bid >> 8, c = bid & 255;
    const int d = threadIdx.x;

    const float w = W_up[((k * 256 + c) * 256) + d];      // coalesced over d
    ((unsigned short*)(ws + OFF_B))[(k * 256 + d) * 256 + c] = f2bf(w);

    // V[k][c] = sum_d w * W_cls[d]  (fp32 tree reduce)
    float p = w * W_cls[d];
    #pragma unroll
    for (int m = 1; m < 64; m <<= 1) p += __shfl_xor(p, m);
    if ((d & 63) == 0) sm[d >> 6] = p;
    __syncthreads();
    if (d == 0)
        ((float*)(ws + OFF_V))[k * 256 + c] = sm[0] + sm[1] + sm[2] + sm[3];

    if (bid == 0) {   // uniform branch: whole block participates
        __syncthreads();
        float q = b_up[d] * W_cls[d];
        #pragma unroll
        for (int m = 1; m < 64; m <<= 1) q += __shfl_xor(q, m);
        if ((d & 63) == 0) sm[d >> 6] = q;
        __syncthreads();
        if (d == 0)
            *((float*)(ws + OFF_EB)) = sm[0] + sm[1] + sm[2] + sm[3] + b_cls[0];
    }
}

// ---------------------------------------------------------------------------
// Kernel 2: zero the target output (output 2). It doubles as the keep-OR mask.
// ---------------------------------------------------------------------------
__global__ __launch_bounds__(256) void zero_kernel(float* __restrict__ out2) {
    int i = blockIdx.x * 256 + threadIdx.x;
    if (i < N_UP) out2[i] = 0.0f;
}

// Kernel 3: scatter target[target_idx] = 1.0 (duplicate writes benign)
__global__ __launch_bounds__(256) void scatter_kernel(
        const int* __restrict__ idx, float* __restrict__ out2) {
    int i = blockIdx.x * 256 + threadIdx.x;
    if (i < N_TGT) out2[idx[i]] = 1.0f;
}

// ---------------------------------------------------------------------------
// Kernel 4: fused bf16-MFMA GEMM [50000 x 256] x [256 x 2048] with
//  - fp32 exist = fea . V[k] + ebias fused into the A-staging pass
//  - keep = (exist > 0) | (target != 0)
//  - masked store of fea_pruned (+b_up), exist written by bn-even blocks.
// BM=128, BN=128 (one k per tile since BN | 256), BK=64, 256 thr = 4 waves 2x2.
// ---------------------------------------------------------------------------
#define BM  128
#define BN  128
#define BK  64
#define LDT 72   // padded LDS row stride (elements); 144 B rows, 16B-aligned

__global__ __launch_bounds__(256) void gemm_kernel(
        const float* __restrict__ fea, const float* __restrict__ b_up,
        const unsigned char* __restrict__ ws,
        float* __restrict__ out0, float* __restrict__ out1,
        const float* __restrict__ target) {
    __shared__ unsigned short As[BM * LDT];   // A tile bf16 [row][c]
    __shared__ unsigned short Bs[BN * LDT];   // B^T tile bf16 [j][c]
    __shared__ float exs[BM];
    __shared__ unsigned char keeps[BM];

    const unsigned short* BbT = (const unsigned short*)(ws + OFF_B);
    const float* V = (const float*)(ws + OFF_V);
    const float ebias = *(const float*)(ws + OFF_EB);

    const int bid = blockIdx.x;
    const int bm = bid >> 4;          // 0..390  (consecutive bids share A-strip)
    const int bn = bid & 15;          // 0..15
    const int m0 = bm * BM;
    const int j0 = bn * BN;
    const int k  = bn >> 1;           // the single child-slot this tile covers

    const int tid  = threadIdx.x;
    const int lane = tid & 63;
    const int wid  = tid >> 6;        // wave 0..3
    const int wr = wid >> 1, wc = wid & 1;     // 2x2 wave grid (64x64 each)
    const int llo = lane & 15, lhi = lane >> 4;

    floatx4 acc[4][4];
    #pragma unroll
    for (int a = 0; a < 4; ++a)
        #pragma unroll
        for (int b = 0; b < 4; ++b) acc[a][b] = (floatx4){0.f, 0.f, 0.f, 0.f};

    float ex[8];
    #pragma unroll
    for (int i = 0; i < 8; ++i) ex[i] = 0.f;

    for (int ks = 0; ks < 4; ++ks) {
        if (ks) __syncthreads();
        const int c0 = ks * BK;

        // ---- stage A (fp32 -> bf16) + fp32 exist partial ----
        const float4 vk = *(const float4*)&V[k * 256 + c0 + llo * 4];
        #pragma unroll
        for (int it = 0; it < 8; ++it) {
            const int r = it * 16 + wid * 4 + lhi;        // bijective 0..127
            int gm = m0 + r;
            if (gm > N_PARENT - 1) gm = N_PARENT - 1;     // clamp (stores guarded)
            const float4 f = *(const float4*)&fea[(size_t)gm * C_IN + c0 + llo * 4];
            ex[it] += f.x * vk.x + f.y * vk.y + f.z * vk.z + f.w * vk.w;
            unsigned long long pk =
                  (unsigned long long)f2bf(f.x)
                | ((unsigned long long)f2bf(f.y) << 16)
                | ((unsigned long long)f2bf(f.z) << 32)
                | ((unsigned long long)f2bf(f.w) << 48);
            *(unsigned long long*)&As[r * LDT + llo * 4] = pk;
        }
        // ---- stage B^T (already bf16 in ws) ----
        #pragma unroll
        for (int it = 0; it < 4; ++it) {
            const int r = it * 32 + wid * 8 + (lane >> 3);
            const uint4 v = *(const uint4*)&BbT[(size_t)(j0 + r) * 256 + c0 + (lane & 7) * 8];
            *(uint4*)&Bs[r * LDT + (lane & 7) * 8] = v;
        }
        __syncthreads();

        // ---- MFMA: 2 k-halves of 32, 4x4 fragment grid per wave ----
        #pragma unroll
        for (int h = 0; h < 2; ++h) {
            short8 af[4], bf[4];
            #pragma unroll
            for (int fm = 0; fm < 4; ++fm)
                af[fm] = *(const short8*)&As[(wr * 64 + fm * 16 + llo) * LDT + h * 32 + lhi * 8];
            #pragma unroll
            for (int fn = 0; fn < 4; ++fn)
                bf[fn] = *(const short8*)&Bs[(wc * 64 + fn * 16 + llo) * LDT + h * 32 + lhi * 8];
            #pragma unroll
            for (int fm = 0; fm < 4; ++fm)
                #pragma unroll
                for (int fn = 0; fn < 4; ++fn)
                    acc[fm][fn] = __builtin_amdgcn_mfma_f32_16x16x32_bf16(
                        af[fm], bf[fn], acc[fm][fn], 0, 0, 0);
        }
    }

    // ---- finish exist: reduce over the 16 chunk-lanes (lane bits 0..3) ----
    #pragma unroll
    for (int m = 1; m < 16; m <<= 1)
        #pragma unroll
        for (int it = 0; it < 8; ++it) ex[it] += __shfl_xor(ex[it], m);

    if (llo == 0) {
        #pragma unroll
        for (int it = 0; it < 8; ++it) {
            const int r = it * 16 + wid * 4 + lhi;
            const float e = ex[it] + ebias;
            exs[r] = e;
            const int n = m0 + r;
            unsigned char kp = 0;
            if (n < N_PARENT)
                kp = (e > 0.0f) || (target[(size_t)n * FANOUT + k] != 0.0f);
            keeps[r] = kp;
        }
    }
    __syncthreads();

    // exist output: one of the two tiles covering this k writes it
    if ((bn & 1) == 0 && tid < BM) {
        const int n = m0 + tid;
        if (n < N_PARENT) out1[(size_t)n * FANOUT + k] = exs[tid];
    }

    // ---- masked store of fea_pruned (+ b_up) ----
    float bup_r[4];
    #pragma unroll
    for (int fn = 0; fn < 4; ++fn)
        bup_r[fn] = b_up[(j0 + wc * 64 + fn * 16 + llo) & 255];

    #pragma unroll
    for (int fm = 0; fm < 4; ++fm) {
        #pragma unroll
        for (int q = 0; q < 4; ++q) {
            const int row = wr * 64 + fm * 16 + lhi * 4 + q;
            const int n = m0 + row;
            if (n >= N_PARENT) continue;
            const bool kp = keeps[row] != 0;
            float* orow = out0 + (size_t)n * NCOL + j0 + wc * 64 + llo;
            #pragma unroll
            for (int fn = 0; fn < 4; ++fn) {
                const float v = kp ? (acc[fm][fn][q] + bup_r[fn]) : 0.0f;
                orow[fn * 16] = v;
            }
        }
    }
}

// ---------------------------------------------------------------------------
extern "C" void kernel_launch(void* const* d_in, const int* in_sizes, int n_in,
                              void* d_out, int out_size, void* d_ws, size_t ws_size,
                              hipStream_t stream) {
    const float* fea   = (const float*)d_in[0];
    const float* W_up  = (const float*)d_in[1];
    const float* b_up  = (const float*)d_in[2];
    const float* W_cls = (const float*)d_in[3];
    const float* b_cls = (const float*)d_in[4];
    const int*   tidx  = (const int*)d_in[5];

    float* out0 = (float*)d_out;                       // fea_pruned [400000,256]
    float* out1 = out0 + (size_t)N_UP * C_OUT;         // exist      [400000,1]
    float* out2 = out1 + N_UP;                         // target     [400000]
    unsigned char* ws = (unsigned char*)d_ws;          // needs ~1.06 MB

    prep_kernel<<<2048, 256, 0, stream>>>(W_up, b_up, W_cls, b_cls, ws);
    zero_kernel<<<(N_UP + 255) / 256, 256, 0, stream>>>(out2);
    scatter_kernel<<<(N_TGT + 255) / 256, 256, 0, stream>>>(tidx, out2);
    gemm_kernel<<<391 * 16, 256, 0, stream>>>(fea, b_up, ws, out0, out1, out2);
}

// Round 2
// 165.699 us; speedup vs baseline: 1.6117x; 1.6117x over previous
//
#include <hip/hip_runtime.h>
#include <hip/hip_bf16.h>

// Problem constants (from reference setup_inputs)
#define N_PARENT 50000
#define C_IN     256
#define C_OUT    256
#define FANOUT   8
#define N_TGT    200000
#define N_UP     (N_PARENT * FANOUT)   // 400000 upsampled rows
#define NCOL     (FANOUT * C_OUT)      // 2048 = fused (k,d) GEMM-N
#define NSTRIP   391                   // ceil(50000/128) M-strips of 128 rows
#define NROWS    (NSTRIP * 128)        // 50048 (rows 50000..50047 are zero pad)

// Workspace layout (~27.1 MB)
//  A strips: bf16, swizzled tile blocks [strip][ks][16KB], 391*64KB
//  B tiles:  bf16, swizzled tile blocks [bn][ks][16KB], 16*64KB = 1MB
// Swizzle within a 16KB (128 rows x 64 cols bf16) block:
//   byte = r*128 + ((cc ^ (r&7))<<4) + lo   where cc = (c_within/8), lo = byte in 16B
#define OFF_A    0u
#define OFF_B    (NSTRIP * 65536u)              // 25,624,576
#define OFF_V    (OFF_B + 16u * 65536u)         // float V[8][256]
#define OFF_EB   (OFF_V + 8192u)                // float ebias
#define OFF_KEEP (OFF_EB + 256u)                // uint8 keep[N_UP]

typedef __attribute__((ext_vector_type(8))) short short8;
typedef __attribute__((ext_vector_type(4))) float floatx4;

static __device__ __forceinline__ unsigned short f2bf(float f) {
    return __builtin_bit_cast(unsigned short, __float2bfloat16(f));
}

static __device__ __forceinline__ void gload_lds16(const void* gsrc, void* ldsdst) {
    __builtin_amdgcn_global_load_lds(
        (const __attribute__((address_space(1))) unsigned int*)gsrc,
        (__attribute__((address_space(3))) unsigned int*)ldsdst, 16, 0, 0);
}

// ---------------------------------------------------------------------------
// Kernel 1: build swizzled bf16 B tiles + V[k][c] = W_up[k] @ W_cls + ebias.
// Grid: 2048 blocks (= k*256 + c), 256 threads (= d). Reads coalesced over d.
// ---------------------------------------------------------------------------
__global__ __launch_bounds__(256) void prep_kernel(
        const float* __restrict__ W_up, const float* __restrict__ b_up,
        const float* __restrict__ W_cls, const float* __restrict__ b_cls,
        unsigned char* __restrict__ ws) {
    __shared__ float sm[4];
    const int bid = blockIdx.x;
    const int k = bid >> 8, c = bid & 255;
    const int d = threadIdx.x;

    const float w = W_up[((k * 256 + c) * 256) + d];      // coalesced over d
    // B^T element: row j = k*256+d -> (bn = j>>7, jr = j&127), col c
    const int bn = (k << 1) | (d >> 7);
    const int jr = d & 127;
    const int ks = c >> 6;
    const int cc = (c >> 3) & 7;
    const int e  = c & 7;
    const unsigned off = OFF_B + (unsigned)bn * 65536u + (unsigned)ks * 16384u
                       + (unsigned)jr * 128u + (unsigned)((cc ^ (jr & 7)) << 4)
                       + (unsigned)(e << 1);
    *(unsigned short*)(ws + off) = f2bf(w);

    // V[k][c] = sum_d w * W_cls[d]  (fp32 tree reduce)
    float p = w * W_cls[d];
    #pragma unroll
    for (int m = 1; m < 64; m <<= 1) p += __shfl_xor(p, m);
    if ((d & 63) == 0) sm[d >> 6] = p;
    __syncthreads();
    if (d == 0)
        ((float*)(ws + OFF_V))[k * 256 + c] = sm[0] + sm[1] + sm[2] + sm[3];

    if (bid == 0) {   // uniform branch: whole block participates
        __syncthreads();
        float q = b_up[d] * W_cls[d];
        #pragma unroll
        for (int m = 1; m < 64; m <<= 1) q += __shfl_xor(q, m);
        if ((d & 63) == 0) sm[d >> 6] = q;
        __syncthreads();
        if (d == 0)
            *((float*)(ws + OFF_EB)) = sm[0] + sm[1] + sm[2] + sm[3] + b_cls[0];
    }
}

// ---------------------------------------------------------------------------
// Kernel 2: zero target output. Kernel 3: scatter target_idx -> 1.0f.
// ---------------------------------------------------------------------------
__global__ __launch_bounds__(256) void zero_kernel(float* __restrict__ out2) {
    int i = blockIdx.x * 256 + threadIdx.x;
    if (i < N_UP) out2[i] = 0.0f;
}

__global__ __launch_bounds__(256) void scatter_kernel(
        const int* __restrict__ idx, float* __restrict__ out2) {
    int i = blockIdx.x * 256 + threadIdx.x;
    if (i < N_TGT) out2[idx[i]] = 1.0f;
}

// ---------------------------------------------------------------------------
// Kernel 4: convert fea -> swizzled bf16 A strips; fp32 exist = fea.V[k]+eb;
//           keep[n*8+k] = (exist>0) | target. One wave per parent row.
// Grid: NROWS/4 blocks x 256 threads (4 waves).
// ---------------------------------------------------------------------------
__global__ __launch_bounds__(256) void convert_kernel(
        const float* __restrict__ fea, const float* __restrict__ target,
        float* __restrict__ out1, unsigned char* __restrict__ ws) {
    const float* V = (const float*)(ws + OFF_V);
    const float eb = *(const float*)(ws + OFF_EB);

    const int rowid = blockIdx.x * 4 + (threadIdx.x >> 6);   // 0..50047
    const int lane  = threadIdx.x & 63;
    const bool valid = rowid < N_PARENT;

    float4 f = make_float4(0.f, 0.f, 0.f, 0.f);
    if (valid) f = *(const float4*)&fea[(size_t)rowid * C_IN + lane * 4];

    float ex[8];
    #pragma unroll
    for (int k = 0; k < 8; ++k) {
        const float4 v = *(const float4*)&V[k * 256 + lane * 4];
        ex[k] = f.x * v.x + f.y * v.y + f.z * v.z + f.w * v.w;
    }

    // write swizzled bf16 A (zeros for pad rows)
    const unsigned long long pk =
          (unsigned long long)f2bf(f.x)
        | ((unsigned long long)f2bf(f.y) << 16)
        | ((unsigned long long)f2bf(f.z) << 32)
        | ((unsigned long long)f2bf(f.w) << 48);
    const int strip = rowid >> 7, r = rowid & 127;
    const int ks = lane >> 4, cc = (lane >> 1) & 7, half = lane & 1;
    const unsigned off = OFF_A + (unsigned)strip * 65536u + (unsigned)ks * 16384u
                       + (unsigned)r * 128u + (unsigned)((cc ^ (r & 7)) << 4)
                       + (unsigned)(half * 8);
    *(unsigned long long*)(ws + off) = pk;

    // full-wave butterfly reduce (all 8 k at once)
    #pragma unroll
    for (int m = 1; m < 64; m <<= 1)
        #pragma unroll
        for (int k = 0; k < 8; ++k) ex[k] += __shfl_xor(ex[k], m);

    if (lane < 8 && valid) {
        float e = ex[0];                       // static-index select (rule #20)
        #pragma unroll
        for (int k = 1; k < 8; ++k) e = (lane == k) ? ex[k] : e;
        e += eb;
        const size_t o = (size_t)rowid * FANOUT + lane;
        out1[o] = e;
        ws[OFF_KEEP + o] = ((e > 0.0f) || (target[o] != 0.0f)) ? 1 : 0;
    }
}

// ---------------------------------------------------------------------------
// Kernel 5: bf16 MFMA GEMM, global_load_lds staging, swizzled ds_read,
// operand-swapped MFMA for float4 stores, XCD-grouped block mapping.
// ---------------------------------------------------------------------------
__global__ __launch_bounds__(256) void gemm_kernel(
        const float* __restrict__ b_up, const unsigned char* __restrict__ ws,
        float* __restrict__ out0) {
    __shared__ unsigned short As[8192];   // 16KB: 128 rows x 64 cols (swizzled)
    __shared__ unsigned short Bs[8192];
    __shared__ unsigned char keeps[128];

    // XCD grouping: all 16 bn-blocks of one bm share bid&7 -> same XCD L2.
    const int bid = blockIdx.x;
    const int g = bid & 7, u = bid >> 3;
    const int t = u >> 4, bn = u & 15;
    const int bm = g + 8 * t;
    if (bm >= NSTRIP) return;              // 16 pad blocks idle

    const unsigned char* Abase = ws + OFF_A + (size_t)bm * 65536u;
    const unsigned char* Bbase = ws + OFF_B + (size_t)bn * 65536u;

    const int tid  = threadIdx.x;
    const int lane = tid & 63;
    const int wid  = tid >> 6;
    const int wr = wid >> 1, wc = wid & 1;    // 2x2 wave grid (64x64 each)
    const int llo = lane & 15, lhi = lane >> 4;

    if (tid < 128) {
        const int n = bm * 128 + tid;
        keeps[tid] = (n < N_PARENT) ? ws[OFF_KEEP + (size_t)n * FANOUT + (bn >> 1)] : 0;
    }

    floatx4 acc[4][4];
    #pragma unroll
    for (int a = 0; a < 4; ++a)
        #pragma unroll
        for (int b = 0; b < 4; ++b) acc[a][b] = (floatx4){0.f, 0.f, 0.f, 0.f};

    for (int ks = 0; ks < 4; ++ks) {
        #pragma unroll
        for (int it = 0; it < 4; ++it)
            gload_lds16(Abase + ks * 16384 + it * 4096 + tid * 16,
                        (char*)As + it * 4096 + tid * 16);
        #pragma unroll
        for (int it = 0; it < 4; ++it)
            gload_lds16(Bbase + ks * 16384 + it * 4096 + tid * 16,
                        (char*)Bs + it * 4096 + tid * 16);
        __syncthreads();

        #pragma unroll
        for (int h = 0; h < 2; ++h) {
            short8 af[4], bf[4];
            #pragma unroll
            for (int fm = 0; fm < 4; ++fm) {
                const int row = wr * 64 + fm * 16 + llo;
                const int ch = (h * 4 + lhi) ^ (row & 7);
                af[fm] = *(const short8*)((const char*)As + row * 128 + ch * 16);
            }
            #pragma unroll
            for (int fn = 0; fn < 4; ++fn) {
                const int row = wc * 64 + fn * 16 + llo;
                const int ch = (h * 4 + lhi) ^ (row & 7);
                bf[fn] = *(const short8*)((const char*)Bs + row * 128 + ch * 16);
            }
            // operand swap: D[j][m] so q spans 4 consecutive output columns
            #pragma unroll
            for (int fm = 0; fm < 4; ++fm)
                #pragma unroll
                for (int fn = 0; fn < 4; ++fn)
                    acc[fm][fn] = __builtin_amdgcn_mfma_f32_16x16x32_bf16(
                        bf[fn], af[fm], acc[fm][fn], 0, 0, 0);
        }
        if (ks < 3) __syncthreads();
    }

    // epilogue: masked float4 stores (+b_up)
    const int j0 = bn * 128;
    #pragma unroll
    for (int fm = 0; fm < 4; ++fm) {
        const int m = bm * 128 + wr * 64 + fm * 16 + llo;
        if (m >= N_PARENT) continue;
        const bool kp = keeps[wr * 64 + fm * 16 + llo] != 0;
        #pragma unroll
        for (int fn = 0; fn < 4; ++fn) {
            const int j = j0 + wc * 64 + fn * 16 + lhi * 4;
            const float4 bv = *(const float4*)&b_up[j & 255];
            const floatx4 a = acc[fm][fn];
            float4 o;
            o.x = kp ? a[0] + bv.x : 0.0f;
            o.y = kp ? a[1] + bv.y : 0.0f;
            o.z = kp ? a[2] + bv.z : 0.0f;
            o.w = kp ? a[3] + bv.w : 0.0f;
            *(float4*)&out0[(size_t)m * NCOL + j] = o;
        }
    }
}

// ---------------------------------------------------------------------------
extern "C" void kernel_launch(void* const* d_in, const int* in_sizes, int n_in,
                              void* d_out, int out_size, void* d_ws, size_t ws_size,
                              hipStream_t stream) {
    const float* fea   = (const float*)d_in[0];
    const float* W_up  = (const float*)d_in[1];
    const float* b_up  = (const float*)d_in[2];
    const float* W_cls = (const float*)d_in[3];
    const float* b_cls = (const float*)d_in[4];
    const int*   tidx  = (const int*)d_in[5];

    float* out0 = (float*)d_out;                       // fea_pruned [400000,256]
    float* out1 = out0 + (size_t)N_UP * C_OUT;         // exist      [400000]
    float* out2 = out1 + N_UP;                         // target     [400000]
    unsigned char* ws = (unsigned char*)d_ws;          // needs ~27.1 MB

    prep_kernel<<<2048, 256, 0, stream>>>(W_up, b_up, W_cls, b_cls, ws);
    zero_kernel<<<(N_UP + 255) / 256, 256, 0, stream>>>(out2);
    scatter_kernel<<<(N_TGT + 255) / 256, 256, 0, stream>>>(tidx, out2);
    convert_kernel<<<NROWS / 4, 256, 0, stream>>>(fea, out2, out1, ws);
    gemm_kernel<<<392 * 16, 256, 0, stream>>>(b_up, ws, out0);
}

// Round 3
// 149.086 us; speedup vs baseline: 1.7912x; 1.1114x over previous
//
#include <hip/hip_runtime.h>
#include <hip/hip_bf16.h>

// Problem constants (from reference setup_inputs)
#define N_PARENT 50000
#define C_IN     256
#define C_OUT    256
#define FANOUT   8
#define N_TGT    200000
#define N_UP     (N_PARENT * FANOUT)   // 400000 upsampled rows
#define NCOL     (FANOUT * C_OUT)      // 2048 = fused (k,d) GEMM-N
#define NSTRIP   391                   // ceil(50000/128) M-strips of 128 rows
#define NROWS    (NSTRIP * 128)        // 50048 (rows 50000..50047 are zero pad)

// Workspace layout (~27.1 MB)
//  A strips: bf16, swizzled tile blocks [strip][ks][16KB], 391*64KB
//  B tiles:  bf16, swizzled tile blocks [bn][ks][16KB], 16*64KB = 1MB
// Swizzle within a 16KB (128 rows x 64 cols bf16) block:
//   byte = r*128 + ((cc ^ (r&7))<<4) + lo   where cc = (c_within/8), lo = byte in 16B
#define OFF_A    0u
#define OFF_B    (NSTRIP * 65536u)              // 25,624,576
#define OFF_V    (OFF_B + 16u * 65536u)         // float V[8][256]
#define OFF_EB   (OFF_V + 8192u)                // float ebias
#define OFF_KEEP (OFF_EB + 256u)                // uint8 keep[N_UP]

typedef __attribute__((ext_vector_type(8))) short short8;
typedef __attribute__((ext_vector_type(4))) float floatx4;

static __device__ __forceinline__ unsigned short f2bf(float f) {
    return __builtin_bit_cast(unsigned short, __float2bfloat16(f));
}

static __device__ __forceinline__ void gload_lds16(const void* gsrc, void* ldsdst) {
    __builtin_amdgcn_global_load_lds(
        (const __attribute__((address_space(1))) unsigned int*)gsrc,
        (__attribute__((address_space(3))) unsigned int*)ldsdst, 16, 0, 0);
}

// ---------------------------------------------------------------------------
// Kernel 1: build swizzled bf16 B tiles + V[k][c] = W_up[k] @ W_cls + ebias,
//           and zero the target output (fused former zero_kernel).
// Grid: 2048 blocks (= k*256 + c), 256 threads (= d). Reads coalesced over d.
// ---------------------------------------------------------------------------
__global__ __launch_bounds__(256) void prep_kernel(
        const float* __restrict__ W_up, const float* __restrict__ b_up,
        const float* __restrict__ W_cls, const float* __restrict__ b_cls,
        unsigned char* __restrict__ ws, float* __restrict__ out2) {
    __shared__ float sm[4];
    const int bid = blockIdx.x;
    const int k = bid >> 8, c = bid & 255;
    const int d = threadIdx.x;

    // fused zero of out2 (100000 float4 across 2048 blocks, 49 each)
    if (d < 49) {
        const int i4 = bid * 49 + d;
        if (i4 < N_UP / 4)
            *(floatx4*)&out2[i4 * 4] = (floatx4){0.f, 0.f, 0.f, 0.f};
    }

    const float w = W_up[((k * 256 + c) * 256) + d];      // coalesced over d
    // B^T element: row j = k*256+d -> (bn = j>>7, jr = j&127), col c
    const int bn = (k << 1) | (d >> 7);
    const int jr = d & 127;
    const int ks = c >> 6;
    const int cc = (c >> 3) & 7;
    const int e  = c & 7;
    const unsigned off = OFF_B + (unsigned)bn * 65536u + (unsigned)ks * 16384u
                       + (unsigned)jr * 128u + (unsigned)((cc ^ (jr & 7)) << 4)
                       + (unsigned)(e << 1);
    *(unsigned short*)(ws + off) = f2bf(w);

    // V[k][c] = sum_d w * W_cls[d]  (fp32 tree reduce)
    float p = w * W_cls[d];
    #pragma unroll
    for (int m = 1; m < 64; m <<= 1) p += __shfl_xor(p, m);
    if ((d & 63) == 0) sm[d >> 6] = p;
    __syncthreads();
    if (d == 0)
        ((float*)(ws + OFF_V))[k * 256 + c] = sm[0] + sm[1] + sm[2] + sm[3];

    if (bid == 0) {   // uniform branch: whole block participates
        __syncthreads();
        float q = b_up[d] * W_cls[d];
        #pragma unroll
        for (int m = 1; m < 64; m <<= 1) q += __shfl_xor(q, m);
        if ((d & 63) == 0) sm[d >> 6] = q;
        __syncthreads();
        if (d == 0)
            *((float*)(ws + OFF_EB)) = sm[0] + sm[1] + sm[2] + sm[3] + b_cls[0];
    }
}

// ---------------------------------------------------------------------------
// Kernel 2: scatter target_idx -> 1.0f (after prep's zeroing).
// ---------------------------------------------------------------------------
__global__ __launch_bounds__(256) void scatter_kernel(
        const int* __restrict__ idx, float* __restrict__ out2) {
    int i = blockIdx.x * 256 + threadIdx.x;
    if (i < N_TGT) out2[idx[i]] = 1.0f;
}

// ---------------------------------------------------------------------------
// Kernel 3: convert fea -> swizzled bf16 A strips; fp32 exist = fea.V[k]+eb;
//           keep[n*8+k] = (exist>0) | target. One wave per parent row.
// Grid: NROWS/4 blocks x 256 threads (4 waves).
// ---------------------------------------------------------------------------
__global__ __launch_bounds__(256) void convert_kernel(
        const float* __restrict__ fea, const float* __restrict__ target,
        float* __restrict__ out1, unsigned char* __restrict__ ws) {
    const float* V = (const float*)(ws + OFF_V);
    const float eb = *(const float*)(ws + OFF_EB);

    const int rowid = blockIdx.x * 4 + (threadIdx.x >> 6);   // 0..50047
    const int lane  = threadIdx.x & 63;
    const bool valid = rowid < N_PARENT;

    floatx4 f = (floatx4){0.f, 0.f, 0.f, 0.f};
    if (valid)
        f = __builtin_nontemporal_load(
                (const floatx4*)&fea[(size_t)rowid * C_IN + lane * 4]);

    float ex[8];
    #pragma unroll
    for (int k = 0; k < 8; ++k) {
        const float4 v = *(const float4*)&V[k * 256 + lane * 4];
        ex[k] = f[0] * v.x + f[1] * v.y + f[2] * v.z + f[3] * v.w;
    }

    // write swizzled bf16 A (zeros for pad rows)
    const unsigned long long pk =
          (unsigned long long)f2bf(f[0])
        | ((unsigned long long)f2bf(f[1]) << 16)
        | ((unsigned long long)f2bf(f[2]) << 32)
        | ((unsigned long long)f2bf(f[3]) << 48);
    const int strip = rowid >> 7, r = rowid & 127;
    const int ks = lane >> 4, cc = (lane >> 1) & 7, half = lane & 1;
    const unsigned off = OFF_A + (unsigned)strip * 65536u + (unsigned)ks * 16384u
                       + (unsigned)r * 128u + (unsigned)((cc ^ (r & 7)) << 4)
                       + (unsigned)(half * 8);
    *(unsigned long long*)(ws + off) = pk;

    // reduce over lane bits 3,4,5 (24 shfl), static 8-way select, then
    // reduce over lane bits 0,1,2 (3 shfl)
    #pragma unroll
    for (int m = 8; m < 64; m <<= 1)
        #pragma unroll
        for (int k = 0; k < 8; ++k) ex[k] += __shfl_xor(ex[k], m);

    const int ksel = lane >> 3;
    float v = ex[0];
    #pragma unroll
    for (int k = 1; k < 8; ++k) v = (ksel == k) ? ex[k] : v;
    #pragma unroll
    for (int m = 1; m < 8; m <<= 1) v += __shfl_xor(v, m);
    v += eb;

    if ((lane & 7) == 0 && valid) {
        const size_t o = (size_t)rowid * FANOUT + ksel;
        out1[o] = v;
        ws[OFF_KEEP + o] = ((v > 0.0f) || (target[o] != 0.0f)) ? 1 : 0;
    }
}

// ---------------------------------------------------------------------------
// Kernel 4: bf16 MFMA GEMM, global_load_lds staging, swizzled ds_read,
// operand-swapped MFMA for float4 stores, XCD-grouped block mapping,
// nontemporal out0 stores (keep L2 for A/B reuse).
// ---------------------------------------------------------------------------
__global__ __launch_bounds__(256) void gemm_kernel(
        const float* __restrict__ b_up, const unsigned char* __restrict__ ws,
        float* __restrict__ out0) {
    __shared__ unsigned short As[8192];   // 16KB: 128 rows x 64 cols (swizzled)
    __shared__ unsigned short Bs[8192];
    __shared__ unsigned char keeps[128];

    // XCD grouping: all 16 bn-blocks of one bm share bid&7 -> same XCD L2.
    const int bid = blockIdx.x;
    const int g = bid & 7, u = bid >> 3;
    const int t = u >> 4, bn = u & 15;
    const int bm = g + 8 * t;
    if (bm >= NSTRIP) return;              // 16 pad blocks idle

    const unsigned char* Abase = ws + OFF_A + (size_t)bm * 65536u;
    const unsigned char* Bbase = ws + OFF_B + (size_t)bn * 65536u;

    const int tid  = threadIdx.x;
    const int lane = tid & 63;
    const int wid  = tid >> 6;
    const int wr = wid >> 1, wc = wid & 1;    // 2x2 wave grid (64x64 each)
    const int llo = lane & 15, lhi = lane >> 4;

    if (tid < 128) {
        const int n = bm * 128 + tid;
        keeps[tid] = (n < N_PARENT) ? ws[OFF_KEEP + (size_t)n * FANOUT + (bn >> 1)] : 0;
    }

    floatx4 acc[4][4];
    #pragma unroll
    for (int a = 0; a < 4; ++a)
        #pragma unroll
        for (int b = 0; b < 4; ++b) acc[a][b] = (floatx4){0.f, 0.f, 0.f, 0.f};

    for (int ks = 0; ks < 4; ++ks) {
        #pragma unroll
        for (int it = 0; it < 4; ++it)
            gload_lds16(Abase + ks * 16384 + it * 4096 + tid * 16,
                        (char*)As + it * 4096 + tid * 16);
        #pragma unroll
        for (int it = 0; it < 4; ++it)
            gload_lds16(Bbase + ks * 16384 + it * 4096 + tid * 16,
                        (char*)Bs + it * 4096 + tid * 16);
        __syncthreads();

        #pragma unroll
        for (int h = 0; h < 2; ++h) {
            short8 af[4], bf[4];
            #pragma unroll
            for (int fm = 0; fm < 4; ++fm) {
                const int row = wr * 64 + fm * 16 + llo;
                const int ch = (h * 4 + lhi) ^ (row & 7);
                af[fm] = *(const short8*)((const char*)As + row * 128 + ch * 16);
            }
            #pragma unroll
            for (int fn = 0; fn < 4; ++fn) {
                const int row = wc * 64 + fn * 16 + llo;
                const int ch = (h * 4 + lhi) ^ (row & 7);
                bf[fn] = *(const short8*)((const char*)Bs + row * 128 + ch * 16);
            }
            // operand swap: D[j][m] so q spans 4 consecutive output columns
            #pragma unroll
            for (int fm = 0; fm < 4; ++fm)
                #pragma unroll
                for (int fn = 0; fn < 4; ++fn)
                    acc[fm][fn] = __builtin_amdgcn_mfma_f32_16x16x32_bf16(
                        bf[fn], af[fm], acc[fm][fn], 0, 0, 0);
        }
        if (ks < 3) __syncthreads();
    }

    // epilogue: masked nontemporal float4 stores (+b_up)
    const int j0 = bn * 128;
    #pragma unroll
    for (int fm = 0; fm < 4; ++fm) {
        const int row = wr * 64 + fm * 16 + llo;
        const int m = bm * 128 + row;
        if (m >= N_PARENT) continue;
        const bool kp = keeps[row] != 0;
        #pragma unroll
        for (int fn = 0; fn < 4; ++fn) {
            const int j = j0 + wc * 64 + fn * 16 + lhi * 4;
            const float4 bv = *(const float4*)&b_up[j & 255];
            const floatx4 a = acc[fm][fn];
            floatx4 o;
            o[0] = kp ? a[0] + bv.x : 0.0f;
            o[1] = kp ? a[1] + bv.y : 0.0f;
            o[2] = kp ? a[2] + bv.z : 0.0f;
            o[3] = kp ? a[3] + bv.w : 0.0f;
            __builtin_nontemporal_store(o, (floatx4*)&out0[(size_t)m * NCOL + j]);
        }
    }
}

// ---------------------------------------------------------------------------
extern "C" void kernel_launch(void* const* d_in, const int* in_sizes, int n_in,
                              void* d_out, int out_size, void* d_ws, size_t ws_size,
                              hipStream_t stream) {
    const float* fea   = (const float*)d_in[0];
    const float* W_up  = (const float*)d_in[1];
    const float* b_up  = (const float*)d_in[2];
    const float* W_cls = (const float*)d_in[3];
    const float* b_cls = (const float*)d_in[4];
    const int*   tidx  = (const int*)d_in[5];

    float* out0 = (float*)d_out;                       // fea_pruned [400000,256]
    float* out1 = out0 + (size_t)N_UP * C_OUT;         // exist      [400000]
    float* out2 = out1 + N_UP;                         // target     [400000]
    unsigned char* ws = (unsigned char*)d_ws;          // needs ~27.1 MB

    prep_kernel<<<2048, 256, 0, stream>>>(W_up, b_up, W_cls, b_cls, ws, out2);
    scatter_kernel<<<(N_TGT + 255) / 256, 256, 0, stream>>>(tidx, out2);
    convert_kernel<<<NROWS / 4, 256, 0, stream>>>(fea, out2, out1, ws);
    gemm_kernel<<<392 * 16, 256, 0, stream>>>(b_up, ws, out0);
}